// Round 7
// baseline (410.347 us; speedup 1.0000x reference)
//
#include <hip/hip_runtime.h>

// ---------------------------------------------------------------------------
// MultiHeadAttention: B=2, S=2048, H=16, Dh=64, D=1024, causal mask, fp32 I/O.
// R7: attention rewritten in transposed-score form (S^T = K·Q^T) so softmax
//     is in-lane along kv (2 shuffles instead of 2x4-step reductions) and
//     P^T feeds PV directly as a B-operand (free k-permutation matched by
//     V^T A-frags) — ZERO LDS / barriers / waitcnt in the kv loop.
//     16 q-rows per wave -> 4096 waves (2x occupancy), K-tile prefetch.
// ---------------------------------------------------------------------------

#define B_   2
#define S_   2048
#define H_   16
#define DH_  64
#define D_   1024
#define M_   (B_ * S_)          // 4096 rows

typedef __attribute__((ext_vector_type(8))) short short8;
typedef __attribute__((ext_vector_type(4))) short short4_t;
typedef float v4f __attribute__((ext_vector_type(4)));

__device__ __forceinline__ short f2bf(float f) {
    union { float f; unsigned u; } v; v.f = f;
    unsigned r = v.u + 0x7fffu + ((v.u >> 16) & 1u);  // round-to-nearest-even
    return (short)(r >> 16);
}

// ---------------------------------------------------------------------------
// Kernel 1: cast Wq,Wk,Wv,Wo fp32 -> bf16 (weights only; 8 elems/thread).
// ---------------------------------------------------------------------------
__global__ __launch_bounds__(256) void castw_kernel(
    const float* __restrict__ Wq, const float* __restrict__ Wk,
    const float* __restrict__ Wv, const float* __restrict__ Wo,
    short* __restrict__ Wb)
{
    const int NW8 = (D_ * D_) / 8;      // 131,072
    int idx = blockIdx.x * 256 + threadIdx.x;   // 524,288 threads
    int sel = idx >> 17;
    int o = idx & (NW8 - 1);
    const float* src = (sel == 0) ? Wq : (sel == 1) ? Wk : (sel == 2) ? Wv : Wo;
    float4 f0 = ((const float4*)src)[o * 2];
    float4 f1 = ((const float4*)src)[o * 2 + 1];
    short8 s;
    s[0] = f2bf(f0.x); s[1] = f2bf(f0.y); s[2] = f2bf(f0.z); s[3] = f2bf(f0.w);
    s[4] = f2bf(f1.x); s[5] = f2bf(f1.y); s[6] = f2bf(f1.z); s[7] = f2bf(f1.w);
    *(short8*)(Wb + (size_t)sel * (D_ * D_) + (size_t)o * 8) = s;
}

// ---------------------------------------------------------------------------
// Kernel 2: C = A @ W(bf16,[N,K])^T + bias.  BM=128, BK=64, register-prefetch
// double buffering, XCD-aware flat-grid swizzle.  (unchanged from R6)
// MODE 0 (BN=128): A = X fp32 (cvt->bf16 at staging). Fused QKV, N=3072.
//   Q,K natural [bh][s][64]; V transposed directly to Vt [bh][64][s].
// MODE 2 (BN=64):  A = Ctx bf16.  fp32 out [M,1024] (final projection).
// ---------------------------------------------------------------------------
template<int BN, int MODE>
__global__ __launch_bounds__(256) void gemm_kernel(
    const void* __restrict__ Av, const short* __restrict__ W,
    const float* __restrict__ bq, const float* __restrict__ bk,
    const float* __restrict__ bv, void* __restrict__ out,
    int M, int N, int K)
{
    __shared__ __align__(16) short smem[(128 + BN) * 72];
    short (*As)[72] = (short(*)[72])smem;
    short (*Bs)[72] = (short(*)[72])(smem + 128 * 72);

    const int t    = threadIdx.x;
    const int lane = t & 63;
    const int wave = t >> 6;

    const int bid = blockIdx.x;
    const int by  = ((bid & 7) << 2) + ((bid >> 3) & 3);
    const int bx  = bid >> 5;
    const int m0 = by * 128;
    const int n0 = bx * BN;

    const int wm = (wave >> 1) * 64;
    const int wn = (wave & 1) * (BN / 2);
    const int NJ = BN / 32;
    const int BIT = BN / 32;

    v4f acc[4][4] = {};

    const int lrow = t >> 3;           // 0..31
    const int lcol = (t & 7) * 8;

    const short* Wp = W + (size_t)(n0 + lrow) * K + lcol;
    uint4 pb[BIT];
    #pragma unroll
    for (int it = 0; it < BIT; ++it) pb[it] = *(const uint4*)(Wp + (size_t)it * 32 * K);

    const float* Apf = (const float*)Av + (size_t)(m0 + lrow) * K + lcol;
    const short* Apb = (const short*)Av + (size_t)(m0 + lrow) * K + lcol;
    float4 paf[4][2];
    uint4  pab[4];
    if constexpr (MODE == 0) {
        #pragma unroll
        for (int it = 0; it < 4; ++it) {
            paf[it][0] = *(const float4*)(Apf + (size_t)it * 32 * K);
            paf[it][1] = *(const float4*)(Apf + (size_t)it * 32 * K + 4);
        }
    } else {
        #pragma unroll
        for (int it = 0; it < 4; ++it) pab[it] = *(const uint4*)(Apb + (size_t)it * 32 * K);
    }

    for (int k0 = 0; k0 < K; k0 += 64) {
        __syncthreads();
        if constexpr (MODE == 0) {
            #pragma unroll
            for (int it = 0; it < 4; ++it) {
                short8 s8;
                s8[0] = f2bf(paf[it][0].x); s8[1] = f2bf(paf[it][0].y);
                s8[2] = f2bf(paf[it][0].z); s8[3] = f2bf(paf[it][0].w);
                s8[4] = f2bf(paf[it][1].x); s8[5] = f2bf(paf[it][1].y);
                s8[6] = f2bf(paf[it][1].z); s8[7] = f2bf(paf[it][1].w);
                *(short8*)&As[lrow + it * 32][lcol] = s8;
            }
        } else {
            #pragma unroll
            for (int it = 0; it < 4; ++it) *(uint4*)&As[lrow + it * 32][lcol] = pab[it];
        }
        #pragma unroll
        for (int it = 0; it < BIT; ++it) *(uint4*)&Bs[lrow + it * 32][lcol] = pb[it];

        if (k0 + 64 < K) {
            if constexpr (MODE == 0) {
                #pragma unroll
                for (int it = 0; it < 4; ++it) {
                    paf[it][0] = *(const float4*)(Apf + (k0 + 64) + (size_t)it * 32 * K);
                    paf[it][1] = *(const float4*)(Apf + (k0 + 64) + (size_t)it * 32 * K + 4);
                }
            } else {
                #pragma unroll
                for (int it = 0; it < 4; ++it)
                    pab[it] = *(const uint4*)(Apb + (k0 + 64) + (size_t)it * 32 * K);
            }
            #pragma unroll
            for (int it = 0; it < BIT; ++it)
                pb[it] = *(const uint4*)(Wp + (k0 + 64) + (size_t)it * 32 * K);
        }
        __syncthreads();

        #pragma unroll
        for (int kk = 0; kk < 2; ++kk) {
            const int fr = lane & 15;
            const int fo = kk * 32 + (lane >> 4) * 8;
            short8 af[4], bf[4];
            #pragma unroll
            for (int i = 0; i < 4; ++i) af[i] = *(const short8*)&As[wm + i * 16 + fr][fo];
            #pragma unroll
            for (int j = 0; j < NJ; ++j) bf[j] = *(const short8*)&Bs[wn + j * 16 + fr][fo];
            #pragma unroll
            for (int i = 0; i < 4; ++i)
                #pragma unroll
                for (int j = 0; j < NJ; ++j)
                    acc[i][j] = __builtin_amdgcn_mfma_f32_16x16x32_bf16(af[i], bf[j], acc[i][j], 0, 0, 0);
        }
    }

    const int lm = lane & 15;
    const int lg = lane >> 4;
    const int sel = n0 >> 10;
    const float* bias = (MODE == 2) ? bq : (sel == 0) ? bq : (sel == 1) ? bk : bv;

    if constexpr (MODE == 2) {
        const int colb = n0 + wn + lm;
        const int rowb = m0 + wm + lg * 4;
        #pragma unroll
        for (int j = 0; j < NJ; ++j) {
            int col = colb + j * 16;
            float bv_ = bias[col];
            #pragma unroll
            for (int i = 0; i < 4; ++i)
                #pragma unroll
                for (int r = 0; r < 4; ++r)
                    ((float*)out)[(size_t)(rowb + i * 16 + r) * 1024 + col] = acc[i][j][r] + bv_;
        }
    } else {
        __syncthreads();
        short* Es = smem + wave * (64 * 72);
        const int cb = (n0 + wn) & 1023;
        #pragma unroll
        for (int j = 0; j < 4; ++j) {
            float bv_ = bias[cb + j * 16 + lm];
            #pragma unroll
            for (int i = 0; i < 4; ++i)
                #pragma unroll
                for (int r = 0; r < 4; ++r) {
                    float vv = acc[i][j][r] + bv_;
                    if (sel < 2)
                        Es[(i * 16 + lg * 4 + r) * 72 + j * 16 + lm] = f2bf(vv);
                    else
                        Es[(j * 16 + lm) * 72 + i * 16 + lg * 4 + r] = f2bf(vv);
                }
        }
        __asm__ __volatile__("s_waitcnt lgkmcnt(0)" ::: "memory");
        short* outQKV = (short*)out;
        const int rl = lane >> 3;
        const int c8 = (lane & 7) * 8;
        const int h  = cb >> 6;
        const int b  = (m0 + wm) >> 11;
        const int bh = (b << 4) + h;
        if (sel < 2) {
            #pragma unroll
            for (int it = 0; it < 8; ++it) {
                int row_l = it * 8 + rl;
                short8 vrow = *(const short8*)&Es[row_l * 72 + c8];
                int s = (m0 + wm + row_l) & 2047;
                *(short8*)(outQKV + (size_t)sel * 4194304 +
                           ((size_t)bh * S_ + s) * DH_ + c8) = vrow;
            }
        } else {
            const int s0 = (m0 + wm) & 2047;
            #pragma unroll
            for (int it = 0; it < 8; ++it) {
                int d_l = it * 8 + rl;
                short8 vrow = *(const short8*)&Es[d_l * 72 + c8];
                *(short8*)(outQKV + (size_t)2 * 4194304 +
                           ((size_t)bh << 17) + ((size_t)d_l << 11) + s0 + c8) = vrow;
            }
        }
    }
}

// ---------------------------------------------------------------------------
// Kernel 3: causal flash attention, transposed-score form.  NO LDS, no
// barriers, no waitcnt in the loop.  Grid: 1024 flat blocks (XCD-swizzled,
// 4 bh per XCD), 4 waves/block, 16 q-rows per wave, paired long/short strips.
//
// S^T = K·Q^T  (A=K: m=kv, B=Q: n=q) -> C holds S^T[kv=j*16+lg*4+r][q=lm]:
// each lane owns 16 kv-scores of ONE q-row -> softmax is in-lane + 2 shuffles.
// PV as O^T = V^T·P^T: P^T is already a valid B-operand under the free MFMA
// k-permutation  kv(k'=lg*8+jj) = kk*32 + 4lg + jj (+16 for jj>=4),
// matched by V^T A-frags loaded as two 8B chunks.
// ---------------------------------------------------------------------------
__global__ __launch_bounds__(256) void attn_kernel(
    const short* __restrict__ Q, const short* __restrict__ Kh,
    const short* __restrict__ Vt, short* __restrict__ ctx)
{
    const int t    = threadIdx.x;
    const int lane = t & 63;
    const int w    = t >> 6;
    const int bid  = blockIdx.x;                 // 1024 blocks
    const int bh   = ((bid & 7) << 2) + ((bid >> 3) & 3);
    const int qp   = bid >> 5;                   // 0..31
    const int p    = (w < 2) ? (qp * 2 + w) : (127 - (qp * 2 + (w - 2)));
    const int qr0  = p * 16;
    const int ktmax = p >> 2;

    const int lm = lane & 15;
    const int lg = lane >> 4;

    const short* Qb = Q  + (size_t)bh * S_ * DH_;
    const short* Kb = Kh + (size_t)bh * S_ * DH_;
    const short* Vb = Vt + ((size_t)bh << 17);

    // Q as B-operand: B[n=q=lm][k=kk*32+lg*8+j]
    short8 qf[2];
    #pragma unroll
    for (int kk = 0; kk < 2; ++kk)
        qf[kk] = *(const short8*)(Qb + (size_t)(qr0 + lm) * DH_ + kk * 32 + lg * 8);

    float m_i = -1e30f, l_i = 0.f;
    v4f o[4] = {};     // O^T[d = i*16 + lg*4 + r][q = lm]

    // K tile 0 as A-operand: A[m=kv=j*16+lm][k=kk*32+lg*8+jj]
    short8 kf[2][4];
    #pragma unroll
    for (int kk = 0; kk < 2; ++kk)
        #pragma unroll
        for (int j = 0; j < 4; ++j)
            kf[kk][j] = *(const short8*)(Kb + (size_t)(j * 16 + lm) * DH_ + kk * 32 + lg * 8);

    for (int kt = 0; kt <= ktmax; ++kt) {
        const int kv0 = kt * 64;

        // V^T A-frags (permuted k): slots 0-3 <- kv0+kk*32+4lg+jj, 4-7 <- +16
        short8 vf[2][4];
        #pragma unroll
        for (int kk = 0; kk < 2; ++kk)
            #pragma unroll
            for (int i = 0; i < 4; ++i) {
                const short* vp = Vb + ((size_t)(i * 16 + lm) << 11) + kv0 + kk * 32 + lg * 4;
                short4_t a = *(const short4_t*)vp;
                short4_t b = *(const short4_t*)(vp + 16);
                vf[kk][i] = __builtin_shufflevector(a, b, 0, 1, 2, 3, 4, 5, 6, 7);
            }

        // S^T = K Q^T
        v4f sc[4] = {};
        #pragma unroll
        for (int kk = 0; kk < 2; ++kk)
            #pragma unroll
            for (int j = 0; j < 4; ++j)
                sc[j] = __builtin_amdgcn_mfma_f32_16x16x32_bf16(kf[kk][j], qf[kk], sc[j], 0, 0, 0);

        // prefetch next K tile (kf already consumed; loads fly during
        // softmax + PV)
        if (kt < ktmax) {
            const int kv1 = kv0 + 64;
            #pragma unroll
            for (int kk = 0; kk < 2; ++kk)
                #pragma unroll
                for (int j = 0; j < 4; ++j)
                    kf[kk][j] = *(const short8*)(Kb + (size_t)(kv1 + j * 16 + lm) * DH_ + kk * 32 + lg * 8);
        }

        // online softmax: in-lane over 16 kv + 2 cross-quad shuffles
        float x[4][4];
        float rm = -1e30f;
        if (kt == ktmax) {
            const int q = qr0 + lm;
            #pragma unroll
            for (int j = 0; j < 4; ++j)
                #pragma unroll
                for (int r = 0; r < 4; ++r) {
                    float v = sc[j][r] * 0.125f;
                    if (kv0 + j * 16 + lg * 4 + r > q) v = -1e30f;
                    x[j][r] = v; rm = fmaxf(rm, v);
                }
        } else {
            #pragma unroll
            for (int j = 0; j < 4; ++j)
                #pragma unroll
                for (int r = 0; r < 4; ++r) {
                    float v = sc[j][r] * 0.125f;
                    x[j][r] = v; rm = fmaxf(rm, v);
                }
        }
        rm = fmaxf(rm, __shfl_xor(rm, 16, 64));
        rm = fmaxf(rm, __shfl_xor(rm, 32, 64));

        const float mn = fmaxf(m_i, rm);
        const float alpha = __expf(m_i - mn);
        m_i = mn;
        float rs = 0.f;
        #pragma unroll
        for (int j = 0; j < 4; ++j)
            #pragma unroll
            for (int r = 0; r < 4; ++r) {
                float e = __expf(x[j][r] - mn);
                x[j][r] = e; rs += e;
            }
        rs += __shfl_xor(rs, 16, 64);
        rs += __shfl_xor(rs, 32, 64);
        l_i = l_i * alpha + rs;
        #pragma unroll
        for (int i = 0; i < 4; ++i) o[i] *= alpha;

        // pack P^T B-frags in-lane (k-permutation matches vf)
        short8 pf[2];
        #pragma unroll
        for (int kk = 0; kk < 2; ++kk)
            #pragma unroll
            for (int jj = 0; jj < 4; ++jj) {
                pf[kk][jj]     = f2bf(x[2 * kk][jj]);
                pf[kk][4 + jj] = f2bf(x[2 * kk + 1][jj]);
            }

        // O^T += V^T P^T
        #pragma unroll
        for (int kk = 0; kk < 2; ++kk)
            #pragma unroll
            for (int i = 0; i < 4; ++i)
                o[i] = __builtin_amdgcn_mfma_f32_16x16x32_bf16(vf[kk][i], pf[kk], o[i], 0, 0, 0);
    }

    // epilogue: ctx[b*S + q][h*64 + d] = O/l, 8B stores per (i)
    const int b = bh >> 4, h = bh & 15;
    const float inv = 1.f / l_i;
    const size_t base = ((size_t)(b * S_ + qr0 + lm) << 10) + (h << 6) + lg * 4;
    #pragma unroll
    for (int i = 0; i < 4; ++i) {
        short4_t s4;
        #pragma unroll
        for (int r = 0; r < 4; ++r) s4[r] = f2bf(o[i][r] * inv);
        *(short4_t*)(ctx + base + i * 16) = s4;
    }
}

// ---------------------------------------------------------------------------
extern "C" void kernel_launch(void* const* d_in, const int* in_sizes, int n_in,
                              void* d_out, int out_size, void* d_ws, size_t ws_size,
                              hipStream_t stream) {
    const float* X  = (const float*)d_in[0];
    const float* Wq = (const float*)d_in[2];
    const float* bq = (const float*)d_in[3];
    const float* Wk = (const float*)d_in[4];
    const float* bk = (const float*)d_in[5];
    const float* Wv = (const float*)d_in[6];
    const float* bv = (const float*)d_in[7];
    const float* Wo = (const float*)d_in[8];
    const float* bo = (const float*)d_in[9];
    float* out = (float*)d_out;

    short* ws  = (short*)d_ws;
    short* Wb  = ws;                          // [Wq|Wk|Wv|Wo] bf16
    short* Qh  = Wb + 4194304;                // [bh][s][64]
    short* Kb  = Qh + 4194304;                // [bh][s][64]
    short* Vt  = Kb + 4194304;                // [bh][64][s] (written by gemm)
    short* Ctx = Vt + 4194304;                // [b*s][1024]

    castw_kernel<<<2048, 256, 0, stream>>>(Wq, Wk, Wv, Wo, Wb);

    gemm_kernel<128, 0><<<768, 256, 0, stream>>>(
        X, Wb, bq, bk, bv, Qh, M_, 3 * D_, D_);

    attn_kernel<<<1024, 256, 0, stream>>>(Qh, Kb, Vt, Ctx);

    gemm_kernel<64, 2><<<512, 256, 0, stream>>>(
        Ctx, Wb + 3145728, bo, bo, bo, out, M_, D_, D_);
}

// Round 8
// 328.412 us; speedup vs baseline: 1.2495x; 1.2495x over previous
//
#include <hip/hip_runtime.h>

// ---------------------------------------------------------------------------
// MultiHeadAttention: B=2, S=2048, H=16, Dh=64, D=1024, causal mask, fp32 I/O.
// R8: transposed-score attention (R7 math, verified) at R6 granularity:
//     32 q-rows/wave via two Q n-frags -> same per-iter loads/MFMA density as
//     R6 but zero LDS / barriers / waitcnt and 2-shuffle softmax.
// ---------------------------------------------------------------------------

#define B_   2
#define S_   2048
#define H_   16
#define DH_  64
#define D_   1024
#define M_   (B_ * S_)          // 4096 rows

typedef __attribute__((ext_vector_type(8))) short short8;
typedef __attribute__((ext_vector_type(4))) short short4_t;
typedef float v4f __attribute__((ext_vector_type(4)));

__device__ __forceinline__ short f2bf(float f) {
    union { float f; unsigned u; } v; v.f = f;
    unsigned r = v.u + 0x7fffu + ((v.u >> 16) & 1u);  // round-to-nearest-even
    return (short)(r >> 16);
}

// ---------------------------------------------------------------------------
// Kernel 1: cast Wq,Wk,Wv,Wo fp32 -> bf16 (weights only; 8 elems/thread).
// ---------------------------------------------------------------------------
__global__ __launch_bounds__(256) void castw_kernel(
    const float* __restrict__ Wq, const float* __restrict__ Wk,
    const float* __restrict__ Wv, const float* __restrict__ Wo,
    short* __restrict__ Wb)
{
    const int NW8 = (D_ * D_) / 8;      // 131,072
    int idx = blockIdx.x * 256 + threadIdx.x;   // 524,288 threads
    int sel = idx >> 17;
    int o = idx & (NW8 - 1);
    const float* src = (sel == 0) ? Wq : (sel == 1) ? Wk : (sel == 2) ? Wv : Wo;
    float4 f0 = ((const float4*)src)[o * 2];
    float4 f1 = ((const float4*)src)[o * 2 + 1];
    short8 s;
    s[0] = f2bf(f0.x); s[1] = f2bf(f0.y); s[2] = f2bf(f0.z); s[3] = f2bf(f0.w);
    s[4] = f2bf(f1.x); s[5] = f2bf(f1.y); s[6] = f2bf(f1.z); s[7] = f2bf(f1.w);
    *(short8*)(Wb + (size_t)sel * (D_ * D_) + (size_t)o * 8) = s;
}

// ---------------------------------------------------------------------------
// Kernel 2: C = A @ W(bf16,[N,K])^T + bias.  BM=128, BK=64, register-prefetch
// double buffering, XCD-aware flat-grid swizzle.  (unchanged from R6)
// MODE 0 (BN=128): A = X fp32 (cvt->bf16 at staging). Fused QKV, N=3072.
//   Q,K natural [bh][s][64]; V transposed directly to Vt [bh][64][s].
// MODE 2 (BN=64):  A = Ctx bf16.  fp32 out [M,1024] (final projection).
// ---------------------------------------------------------------------------
template<int BN, int MODE>
__global__ __launch_bounds__(256) void gemm_kernel(
    const void* __restrict__ Av, const short* __restrict__ W,
    const float* __restrict__ bq, const float* __restrict__ bk,
    const float* __restrict__ bv, void* __restrict__ out,
    int M, int N, int K)
{
    __shared__ __align__(16) short smem[(128 + BN) * 72];
    short (*As)[72] = (short(*)[72])smem;
    short (*Bs)[72] = (short(*)[72])(smem + 128 * 72);

    const int t    = threadIdx.x;
    const int lane = t & 63;
    const int wave = t >> 6;

    const int bid = blockIdx.x;
    const int by  = ((bid & 7) << 2) + ((bid >> 3) & 3);
    const int bx  = bid >> 5;
    const int m0 = by * 128;
    const int n0 = bx * BN;

    const int wm = (wave >> 1) * 64;
    const int wn = (wave & 1) * (BN / 2);
    const int NJ = BN / 32;
    const int BIT = BN / 32;

    v4f acc[4][4] = {};

    const int lrow = t >> 3;           // 0..31
    const int lcol = (t & 7) * 8;

    const short* Wp = W + (size_t)(n0 + lrow) * K + lcol;
    uint4 pb[BIT];
    #pragma unroll
    for (int it = 0; it < BIT; ++it) pb[it] = *(const uint4*)(Wp + (size_t)it * 32 * K);

    const float* Apf = (const float*)Av + (size_t)(m0 + lrow) * K + lcol;
    const short* Apb = (const short*)Av + (size_t)(m0 + lrow) * K + lcol;
    float4 paf[4][2];
    uint4  pab[4];
    if constexpr (MODE == 0) {
        #pragma unroll
        for (int it = 0; it < 4; ++it) {
            paf[it][0] = *(const float4*)(Apf + (size_t)it * 32 * K);
            paf[it][1] = *(const float4*)(Apf + (size_t)it * 32 * K + 4);
        }
    } else {
        #pragma unroll
        for (int it = 0; it < 4; ++it) pab[it] = *(const uint4*)(Apb + (size_t)it * 32 * K);
    }

    for (int k0 = 0; k0 < K; k0 += 64) {
        __syncthreads();
        if constexpr (MODE == 0) {
            #pragma unroll
            for (int it = 0; it < 4; ++it) {
                short8 s8;
                s8[0] = f2bf(paf[it][0].x); s8[1] = f2bf(paf[it][0].y);
                s8[2] = f2bf(paf[it][0].z); s8[3] = f2bf(paf[it][0].w);
                s8[4] = f2bf(paf[it][1].x); s8[5] = f2bf(paf[it][1].y);
                s8[6] = f2bf(paf[it][1].z); s8[7] = f2bf(paf[it][1].w);
                *(short8*)&As[lrow + it * 32][lcol] = s8;
            }
        } else {
            #pragma unroll
            for (int it = 0; it < 4; ++it) *(uint4*)&As[lrow + it * 32][lcol] = pab[it];
        }
        #pragma unroll
        for (int it = 0; it < BIT; ++it) *(uint4*)&Bs[lrow + it * 32][lcol] = pb[it];

        if (k0 + 64 < K) {
            if constexpr (MODE == 0) {
                #pragma unroll
                for (int it = 0; it < 4; ++it) {
                    paf[it][0] = *(const float4*)(Apf + (k0 + 64) + (size_t)it * 32 * K);
                    paf[it][1] = *(const float4*)(Apf + (k0 + 64) + (size_t)it * 32 * K + 4);
                }
            } else {
                #pragma unroll
                for (int it = 0; it < 4; ++it)
                    pab[it] = *(const uint4*)(Apb + (k0 + 64) + (size_t)it * 32 * K);
            }
            #pragma unroll
            for (int it = 0; it < BIT; ++it)
                pb[it] = *(const uint4*)(Wp + (k0 + 64) + (size_t)it * 32 * K);
        }
        __syncthreads();

        #pragma unroll
        for (int kk = 0; kk < 2; ++kk) {
            const int fr = lane & 15;
            const int fo = kk * 32 + (lane >> 4) * 8;
            short8 af[4], bf[4];
            #pragma unroll
            for (int i = 0; i < 4; ++i) af[i] = *(const short8*)&As[wm + i * 16 + fr][fo];
            #pragma unroll
            for (int j = 0; j < NJ; ++j) bf[j] = *(const short8*)&Bs[wn + j * 16 + fr][fo];
            #pragma unroll
            for (int i = 0; i < 4; ++i)
                #pragma unroll
                for (int j = 0; j < NJ; ++j)
                    acc[i][j] = __builtin_amdgcn_mfma_f32_16x16x32_bf16(af[i], bf[j], acc[i][j], 0, 0, 0);
        }
    }

    const int lm = lane & 15;
    const int lg = lane >> 4;
    const int sel = n0 >> 10;
    const float* bias = (MODE == 2) ? bq : (sel == 0) ? bq : (sel == 1) ? bk : bv;

    if constexpr (MODE == 2) {
        const int colb = n0 + wn + lm;
        const int rowb = m0 + wm + lg * 4;
        #pragma unroll
        for (int j = 0; j < NJ; ++j) {
            int col = colb + j * 16;
            float bv_ = bias[col];
            #pragma unroll
            for (int i = 0; i < 4; ++i)
                #pragma unroll
                for (int r = 0; r < 4; ++r)
                    ((float*)out)[(size_t)(rowb + i * 16 + r) * 1024 + col] = acc[i][j][r] + bv_;
        }
    } else {
        __syncthreads();
        short* Es = smem + wave * (64 * 72);
        const int cb = (n0 + wn) & 1023;
        #pragma unroll
        for (int j = 0; j < 4; ++j) {
            float bv_ = bias[cb + j * 16 + lm];
            #pragma unroll
            for (int i = 0; i < 4; ++i)
                #pragma unroll
                for (int r = 0; r < 4; ++r) {
                    float vv = acc[i][j][r] + bv_;
                    if (sel < 2)
                        Es[(i * 16 + lg * 4 + r) * 72 + j * 16 + lm] = f2bf(vv);
                    else
                        Es[(j * 16 + lm) * 72 + i * 16 + lg * 4 + r] = f2bf(vv);
                }
        }
        __asm__ __volatile__("s_waitcnt lgkmcnt(0)" ::: "memory");
        short* outQKV = (short*)out;
        const int rl = lane >> 3;
        const int c8 = (lane & 7) * 8;
        const int h  = cb >> 6;
        const int b  = (m0 + wm) >> 11;
        const int bh = (b << 4) + h;
        if (sel < 2) {
            #pragma unroll
            for (int it = 0; it < 8; ++it) {
                int row_l = it * 8 + rl;
                short8 vrow = *(const short8*)&Es[row_l * 72 + c8];
                int s = (m0 + wm + row_l) & 2047;
                *(short8*)(outQKV + (size_t)sel * 4194304 +
                           ((size_t)bh * S_ + s) * DH_ + c8) = vrow;
            }
        } else {
            const int s0 = (m0 + wm) & 2047;
            #pragma unroll
            for (int it = 0; it < 8; ++it) {
                int d_l = it * 8 + rl;
                short8 vrow = *(const short8*)&Es[d_l * 72 + c8];
                *(short8*)(outQKV + (size_t)2 * 4194304 +
                           ((size_t)bh << 17) + ((size_t)d_l << 11) + s0 + c8) = vrow;
            }
        }
    }
}

// ---------------------------------------------------------------------------
// Kernel 3: causal flash attention, transposed-score form, 32 q-rows/wave.
// No LDS, no barriers, no waitcnt in the kv loop.
// Grid: 512 flat blocks (XCD-swizzled, 4 bh/XCD), 4 waves, paired strips.
//
// S^T = K·Q^T: A=K (m=kv), B=Q (n=q, two 16-col groups t2).  C holds
// S^T[kv=j*16+lg*4+r][q=t2*16+lm]: softmax in-lane over 16 kv + 2 shuffles.
// PV as O^T = V^T·P^T with the free k-permutation
//   kv(k'=lg*8+jj) = kk*32 + 4*lg + jj (+16 for jj>=4),
// matched by V^T A-frags loaded as two 8B chunks.  (verified in R7)
// ---------------------------------------------------------------------------
__global__ __launch_bounds__(256) void attn_kernel(
    const short* __restrict__ Q, const short* __restrict__ Kh,
    const short* __restrict__ Vt, short* __restrict__ ctx)
{
    const int t    = threadIdx.x;
    const int lane = t & 63;
    const int w    = t >> 6;
    const int bid  = blockIdx.x;                 // 512 blocks
    const int bh   = ((bid & 7) << 2) + ((bid >> 3) & 3);
    const int qp   = bid >> 5;                   // 0..15
    const int p    = (w < 2) ? (qp * 2 + w) : (63 - (qp * 2 + (w - 2)));
    const int qr0  = p * 32;
    const int ktmax = p >> 1;                    // (qr0+31)>>6

    const int lm = lane & 15;
    const int lg = lane >> 4;

    const short* Qb = Q  + (size_t)bh * S_ * DH_;
    const short* Kb = Kh + (size_t)bh * S_ * DH_;
    const short* Vb = Vt + ((size_t)bh << 17);

    // Q as B-operand, two q-groups: B[n=q=qr0+t2*16+lm][k=kk*32+lg*8+j]
    short8 qf[2][2];
    #pragma unroll
    for (int t2 = 0; t2 < 2; ++t2)
        #pragma unroll
        for (int kk = 0; kk < 2; ++kk)
            qf[t2][kk] = *(const short8*)(Qb + (size_t)(qr0 + t2 * 16 + lm) * DH_ + kk * 32 + lg * 8);

    float m_i[2] = {-1e30f, -1e30f}, l_i[2] = {0.f, 0.f};
    v4f o[2][4] = {};   // O^T[d = i*16+lg*4+r][q = t2*16+lm]

    // K tile 0 as A-operand: A[m=kv=j*16+lm][k=kk*32+lg*8+jj]
    short8 kf[2][4];
    #pragma unroll
    for (int kk = 0; kk < 2; ++kk)
        #pragma unroll
        for (int j = 0; j < 4; ++j)
            kf[kk][j] = *(const short8*)(Kb + (size_t)(j * 16 + lm) * DH_ + kk * 32 + lg * 8);

    for (int kt = 0; kt <= ktmax; ++kt) {
        const int kv0 = kt * 64;

        // V^T A-frags (permuted k): slots 0-3 <- kv0+kk*32+4lg+jj, 4-7 <- +16
        short8 vf[2][4];
        #pragma unroll
        for (int kk = 0; kk < 2; ++kk)
            #pragma unroll
            for (int i = 0; i < 4; ++i) {
                const short* vp = Vb + ((size_t)(i * 16 + lm) << 11) + kv0 + kk * 32 + lg * 4;
                short4_t a = *(const short4_t*)vp;
                short4_t b = *(const short4_t*)(vp + 16);
                vf[kk][i] = __builtin_shufflevector(a, b, 0, 1, 2, 3, 4, 5, 6, 7);
            }

        // S^T = K Q^T   (16 MFMAs)
        v4f sc[2][4] = {};
        #pragma unroll
        for (int kk = 0; kk < 2; ++kk)
            #pragma unroll
            for (int t2 = 0; t2 < 2; ++t2)
                #pragma unroll
                for (int j = 0; j < 4; ++j)
                    sc[t2][j] = __builtin_amdgcn_mfma_f32_16x16x32_bf16(kf[kk][j], qf[t2][kk], sc[t2][j], 0, 0, 0);

        // prefetch next K tile (kf consumed; loads fly during softmax+PV)
        if (kt < ktmax) {
            const int kv1 = kv0 + 64;
            #pragma unroll
            for (int kk = 0; kk < 2; ++kk)
                #pragma unroll
                for (int j = 0; j < 4; ++j)
                    kf[kk][j] = *(const short8*)(Kb + (size_t)(kv1 + j * 16 + lm) * DH_ + kk * 32 + lg * 8);
        }

        // online softmax per q-group: in-lane over 16 kv + 2 shuffles
        short8 pf[2][2];
        float alpha[2];
        #pragma unroll
        for (int t2 = 0; t2 < 2; ++t2) {
            float x[4][4];
            float rm = -1e30f;
            if (kt == ktmax) {
                const int q = qr0 + t2 * 16 + lm;
                #pragma unroll
                for (int j = 0; j < 4; ++j)
                    #pragma unroll
                    for (int r = 0; r < 4; ++r) {
                        float v = sc[t2][j][r] * 0.125f;
                        if (kv0 + j * 16 + lg * 4 + r > q) v = -1e30f;
                        x[j][r] = v; rm = fmaxf(rm, v);
                    }
            } else {
                #pragma unroll
                for (int j = 0; j < 4; ++j)
                    #pragma unroll
                    for (int r = 0; r < 4; ++r) {
                        float v = sc[t2][j][r] * 0.125f;
                        x[j][r] = v; rm = fmaxf(rm, v);
                    }
            }
            rm = fmaxf(rm, __shfl_xor(rm, 16, 64));
            rm = fmaxf(rm, __shfl_xor(rm, 32, 64));

            const float mn = fmaxf(m_i[t2], rm);
            alpha[t2] = __expf(m_i[t2] - mn);
            m_i[t2] = mn;
            float rs = 0.f;
            #pragma unroll
            for (int j = 0; j < 4; ++j)
                #pragma unroll
                for (int r = 0; r < 4; ++r) {
                    float e = __expf(x[j][r] - mn);
                    x[j][r] = e; rs += e;
                }
            rs += __shfl_xor(rs, 16, 64);
            rs += __shfl_xor(rs, 32, 64);
            l_i[t2] = l_i[t2] * alpha[t2] + rs;

            // pack P^T B-frags in-lane (k-permutation matches vf)
            #pragma unroll
            for (int kk = 0; kk < 2; ++kk)
                #pragma unroll
                for (int jj = 0; jj < 4; ++jj) {
                    pf[t2][kk][jj]     = f2bf(x[2 * kk][jj]);
                    pf[t2][kk][4 + jj] = f2bf(x[2 * kk + 1][jj]);
                }
        }

        #pragma unroll
        for (int t2 = 0; t2 < 2; ++t2)
            #pragma unroll
            for (int i = 0; i < 4; ++i)
                o[t2][i] *= alpha[t2];

        // O^T += V^T P^T   (16 MFMAs)
        #pragma unroll
        for (int kk = 0; kk < 2; ++kk)
            #pragma unroll
            for (int t2 = 0; t2 < 2; ++t2)
                #pragma unroll
                for (int i = 0; i < 4; ++i)
                    o[t2][i] = __builtin_amdgcn_mfma_f32_16x16x32_bf16(vf[kk][i], pf[t2][kk], o[t2][i], 0, 0, 0);
    }

    // epilogue: ctx[b*S + q][h*64 + d] = O/l, 8B stores
    const int b = bh >> 4, h = bh & 15;
    #pragma unroll
    for (int t2 = 0; t2 < 2; ++t2) {
        const float inv = 1.f / l_i[t2];
        const size_t base = ((size_t)(b * S_ + qr0 + t2 * 16 + lm) << 10) + (h << 6) + lg * 4;
        #pragma unroll
        for (int i = 0; i < 4; ++i) {
            short4_t s4;
            #pragma unroll
            for (int r = 0; r < 4; ++r) s4[r] = f2bf(o[t2][i][r] * inv);
            *(short4_t*)(ctx + base + i * 16) = s4;
        }
    }
}

// ---------------------------------------------------------------------------
extern "C" void kernel_launch(void* const* d_in, const int* in_sizes, int n_in,
                              void* d_out, int out_size, void* d_ws, size_t ws_size,
                              hipStream_t stream) {
    const float* X  = (const float*)d_in[0];
    const float* Wq = (const float*)d_in[2];
    const float* bq = (const float*)d_in[3];
    const float* Wk = (const float*)d_in[4];
    const float* bk = (const float*)d_in[5];
    const float* Wv = (const float*)d_in[6];
    const float* bv = (const float*)d_in[7];
    const float* Wo = (const float*)d_in[8];
    const float* bo = (const float*)d_in[9];
    float* out = (float*)d_out;

    short* ws  = (short*)d_ws;
    short* Wb  = ws;                          // [Wq|Wk|Wv|Wo] bf16
    short* Qh  = Wb + 4194304;                // [bh][s][64]
    short* Kb  = Qh + 4194304;                // [bh][s][64]
    short* Vt  = Kb + 4194304;                // [bh][64][s] (written by gemm)
    short* Ctx = Vt + 4194304;                // [b*s][1024]

    castw_kernel<<<2048, 256, 0, stream>>>(Wq, Wk, Wv, Wo, Wb);

    gemm_kernel<128, 0><<<768, 256, 0, stream>>>(
        X, Wb, bq, bk, bv, Qh, M_, 3 * D_, D_);

    attn_kernel<<<512, 256, 0, stream>>>(Qh, Kb, Vt, Ctx);

    gemm_kernel<64, 2><<<512, 256, 0, stream>>>(
        Ctx, Wb + 3145728, bo, bo, bo, out, M_, D_, D_);
}

// Round 9
// 269.530 us; speedup vs baseline: 1.5225x; 1.2185x over previous
//
#include <hip/hip_runtime.h>

// ---------------------------------------------------------------------------
// MultiHeadAttention: B=2, S=2048, H=16, Dh=64, D=1024, causal mask, fp32 I/O.
// R9: m97-style GEMMs — global_load_lds(16B) async staging into unpadded LDS,
//     2-barrier K-loop, zero prefetch VGPRs.  X pre-cast to bf16.  Out-proj
//     at BN=128 (256 blocks).  Attention = R8 transposed-score (verified).
// ---------------------------------------------------------------------------

#define B_   2
#define S_   2048
#define H_   16
#define DH_  64
#define D_   1024
#define M_   (B_ * S_)          // 4096 rows

typedef __attribute__((ext_vector_type(8))) short short8;
typedef __attribute__((ext_vector_type(4))) short short4_t;
typedef float v4f __attribute__((ext_vector_type(4)));

__device__ __forceinline__ short f2bf(float f) {
    union { float f; unsigned u; } v; v.f = f;
    unsigned r = v.u + 0x7fffu + ((v.u >> 16) & 1u);  // round-to-nearest-even
    return (short)(r >> 16);
}

// async 16B/lane global -> LDS DMA (lane l deposits at lds + l*16)
__device__ __forceinline__ void gl2lds16(const short* g, short* l) {
    __builtin_amdgcn_global_load_lds(
        (const __attribute__((address_space(1))) unsigned int*)g,
        (__attribute__((address_space(3))) unsigned int*)l,
        16, 0, 0);
}

// ---------------------------------------------------------------------------
// Kernel 1: cast X and Wq,Wk,Wv,Wo fp32 -> bf16.  8 elems/thread, 16B stores.
// ---------------------------------------------------------------------------
__global__ __launch_bounds__(256) void cast_kernel(
    const float* __restrict__ X,
    const float* __restrict__ Wq, const float* __restrict__ Wk,
    const float* __restrict__ Wv, const float* __restrict__ Wo,
    short* __restrict__ Xb, short* __restrict__ Wb)
{
    const int NX8 = (M_ * D_) / 8;      // 524,288
    const int NW8 = (D_ * D_) / 8;      // 131,072
    int idx = blockIdx.x * 256 + threadIdx.x;   // 1,048,576 threads

    const float* src; short* dst; int off;
    if (idx < NX8) { src = X; dst = Xb; off = idx; }
    else {
        int r = idx - NX8;
        int sel = r >> 17;
        int o = r & (NW8 - 1);
        src = (sel == 0) ? Wq : (sel == 1) ? Wk : (sel == 2) ? Wv : Wo;
        dst = Wb + sel * (D_ * D_);
        off = o;
    }
    float4 f0 = ((const float4*)src)[off * 2];
    float4 f1 = ((const float4*)src)[off * 2 + 1];
    short8 s;
    s[0] = f2bf(f0.x); s[1] = f2bf(f0.y); s[2] = f2bf(f0.z); s[3] = f2bf(f0.w);
    s[4] = f2bf(f1.x); s[5] = f2bf(f1.y); s[6] = f2bf(f1.z); s[7] = f2bf(f1.w);
    *(short8*)(dst + (size_t)off * 8) = s;
}

// ---------------------------------------------------------------------------
// Kernel 2: C = A(bf16,[M,K]) @ W(bf16,[N,K])^T + bias.  BM=BN=128, BK=64.
// Staging: 8 global_load_lds dwordx4 per wave per k-iter into UNPADDED
// row-major [128][64] LDS tiles (DMA lane-order forbids padding).
// MODE 0: fused QKV, N=3072.  Q,K natural [bh][s][64]; V -> Vt [bh][64][s]
//         via transposed LDS epilogue, 16B/lane stores.
// MODE 2: fp32 out [M,1024] (final projection).
// XCD-aware flat-grid swizzle: xcd=bid&7 owns 4 m-rows.
// ---------------------------------------------------------------------------
template<int MODE>
__global__ __launch_bounds__(256) void gemm_kernel(
    const short* __restrict__ A, const short* __restrict__ W,
    const float* __restrict__ bq, const float* __restrict__ bk,
    const float* __restrict__ bv, void* __restrict__ out,
    int M, int N, int K)
{
    __shared__ __align__(16) short smem[18432];        // 36,864 B
    short* As = smem;                                  // [128][64]
    short* Bs = smem + 8192;                           // [128][64]

    const int t    = threadIdx.x;
    const int lane = t & 63;
    const int wave = t >> 6;

    const int bid = blockIdx.x;
    const int by  = ((bid & 7) << 2) + ((bid >> 3) & 3);
    const int bx  = bid >> 5;
    const int m0 = by * 128;
    const int n0 = bx * 128;

    const int wm = (wave >> 1) * 64;
    const int wn = (wave & 1) * 64;

    v4f acc[4][4] = {};

    // staging address components: inst i2 covers rows wave*32+i2*8..+7,
    // lane l -> row +(l>>3), col (l&7)*8  (matches DMA lane order)
    const int rsub = lane >> 3;
    const int csub = (lane & 7) * 8;
    const short* Ag = A + (size_t)(m0 + wave * 32 + rsub) * K + csub;
    const short* Wg = W + (size_t)(n0 + wave * 32 + rsub) * K + csub;
    short* Asw = As + (wave * 32) * 64;
    short* Bsw = Bs + (wave * 32) * 64;

    const int lm = lane & 15;
    const int lg = lane >> 4;

    for (int k0 = 0; k0 < K; k0 += 64) {
        #pragma unroll
        for (int i2 = 0; i2 < 4; ++i2) {
            gl2lds16(Ag + (size_t)(i2 * 8) * K + k0, Asw + i2 * 512);
            gl2lds16(Wg + (size_t)(i2 * 8) * K + k0, Bsw + i2 * 512);
        }
        __syncthreads();   // drains vmcnt(0): tiles visible

        #pragma unroll
        for (int kk = 0; kk < 2; ++kk) {
            const int fo = kk * 32 + lg * 8;
            short8 af[4], bf[4];
            #pragma unroll
            for (int i = 0; i < 4; ++i) af[i] = *(const short8*)&As[(wm + i * 16 + lm) * 64 + fo];
            #pragma unroll
            for (int j = 0; j < 4; ++j) bf[j] = *(const short8*)&Bs[(wn + j * 16 + lm) * 64 + fo];
            #pragma unroll
            for (int i = 0; i < 4; ++i)
                #pragma unroll
                for (int j = 0; j < 4; ++j)
                    acc[i][j] = __builtin_amdgcn_mfma_f32_16x16x32_bf16(af[i], bf[j], acc[i][j], 0, 0, 0);
        }
        __syncthreads();   // all reads done before next overwrite
    }

    const int sel = n0 >> 10;          // 0=Q 1=K 2=V (block-uniform, MODE 0)
    const float* bias = (MODE == 2) ? bq : (sel == 0) ? bq : (sel == 1) ? bk : bv;

    if constexpr (MODE == 2) {
        // fp32 direct: 16 lanes per quad cover a full 64B line per store.
        const int colb = n0 + wn + lm;
        const int rowb = m0 + wm + lg * 4;
        #pragma unroll
        for (int j = 0; j < 4; ++j) {
            int col = colb + j * 16;
            float bv_ = bias[col];
            #pragma unroll
            for (int i = 0; i < 4; ++i)
                #pragma unroll
                for (int r = 0; r < 4; ++r)
                    ((float*)out)[(size_t)(rowb + i * 16 + r) * 1024 + col] = acc[i][j][r] + bv_;
        }
    } else {
        // bf16 via wave-private LDS region (72-padded); 16B/lane wide stores.
        short* Es = smem + wave * (64 * 72);
        const int cb = (n0 + wn) & 1023;
        #pragma unroll
        for (int j = 0; j < 4; ++j) {
            float bv_ = bias[cb + j * 16 + lm];
            #pragma unroll
            for (int i = 0; i < 4; ++i)
                #pragma unroll
                for (int r = 0; r < 4; ++r) {
                    float vv = acc[i][j][r] + bv_;
                    if (sel < 2)    // Es[s_local][d]
                        Es[(i * 16 + lg * 4 + r) * 72 + j * 16 + lm] = f2bf(vv);
                    else            // V: Es[d][s_local]  (transposed)
                        Es[(j * 16 + lm) * 72 + i * 16 + lg * 4 + r] = f2bf(vv);
                }
        }
        __asm__ __volatile__("s_waitcnt lgkmcnt(0)" ::: "memory");
        short* outQKV = (short*)out;           // [Qh | Kb | Vt]
        const int rl = lane >> 3;
        const int c8 = (lane & 7) * 8;
        const int h  = cb >> 6;
        const int b  = (m0 + wm) >> 11;
        const int bh = (b << 4) + h;
        if (sel < 2) {
            #pragma unroll
            for (int it = 0; it < 8; ++it) {
                int row_l = it * 8 + rl;
                short8 vrow = *(const short8*)&Es[row_l * 72 + c8];
                int s = (m0 + wm + row_l) & 2047;
                *(short8*)(outQKV + (size_t)sel * 4194304 +
                           ((size_t)bh * S_ + s) * DH_ + c8) = vrow;
            }
        } else {
            const int s0 = (m0 + wm) & 2047;
            #pragma unroll
            for (int it = 0; it < 8; ++it) {
                int d_l = it * 8 + rl;
                short8 vrow = *(const short8*)&Es[d_l * 72 + c8];
                *(short8*)(outQKV + (size_t)2 * 4194304 +
                           ((size_t)bh << 17) + ((size_t)d_l << 11) + s0 + c8) = vrow;
            }
        }
    }
}

// ---------------------------------------------------------------------------
// Kernel 3: causal flash attention, transposed-score form, 32 q-rows/wave.
// No LDS, no barriers, no waitcnt in the kv loop.  (R8, verified)
// ---------------------------------------------------------------------------
__global__ __launch_bounds__(256) void attn_kernel(
    const short* __restrict__ Q, const short* __restrict__ Kh,
    const short* __restrict__ Vt, short* __restrict__ ctx)
{
    const int t    = threadIdx.x;
    const int lane = t & 63;
    const int w    = t >> 6;
    const int bid  = blockIdx.x;                 // 512 blocks
    const int bh   = ((bid & 7) << 2) + ((bid >> 3) & 3);
    const int qp   = bid >> 5;                   // 0..15
    const int p    = (w < 2) ? (qp * 2 + w) : (63 - (qp * 2 + (w - 2)));
    const int qr0  = p * 32;
    const int ktmax = p >> 1;

    const int lm = lane & 15;
    const int lg = lane >> 4;

    const short* Qb = Q  + (size_t)bh * S_ * DH_;
    const short* Kb = Kh + (size_t)bh * S_ * DH_;
    const short* Vb = Vt + ((size_t)bh << 17);

    short8 qf[2][2];
    #pragma unroll
    for (int t2 = 0; t2 < 2; ++t2)
        #pragma unroll
        for (int kk = 0; kk < 2; ++kk)
            qf[t2][kk] = *(const short8*)(Qb + (size_t)(qr0 + t2 * 16 + lm) * DH_ + kk * 32 + lg * 8);

    float m_i[2] = {-1e30f, -1e30f}, l_i[2] = {0.f, 0.f};
    v4f o[2][4] = {};

    short8 kf[2][4];
    #pragma unroll
    for (int kk = 0; kk < 2; ++kk)
        #pragma unroll
        for (int j = 0; j < 4; ++j)
            kf[kk][j] = *(const short8*)(Kb + (size_t)(j * 16 + lm) * DH_ + kk * 32 + lg * 8);

    for (int kt = 0; kt <= ktmax; ++kt) {
        const int kv0 = kt * 64;

        short8 vf[2][4];
        #pragma unroll
        for (int kk = 0; kk < 2; ++kk)
            #pragma unroll
            for (int i = 0; i < 4; ++i) {
                const short* vp = Vb + ((size_t)(i * 16 + lm) << 11) + kv0 + kk * 32 + lg * 4;
                short4_t a = *(const short4_t*)vp;
                short4_t b = *(const short4_t*)(vp + 16);
                vf[kk][i] = __builtin_shufflevector(a, b, 0, 1, 2, 3, 4, 5, 6, 7);
            }

        v4f sc[2][4] = {};
        #pragma unroll
        for (int kk = 0; kk < 2; ++kk)
            #pragma unroll
            for (int t2 = 0; t2 < 2; ++t2)
                #pragma unroll
                for (int j = 0; j < 4; ++j)
                    sc[t2][j] = __builtin_amdgcn_mfma_f32_16x16x32_bf16(kf[kk][j], qf[t2][kk], sc[t2][j], 0, 0, 0);

        if (kt < ktmax) {
            const int kv1 = kv0 + 64;
            #pragma unroll
            for (int kk = 0; kk < 2; ++kk)
                #pragma unroll
                for (int j = 0; j < 4; ++j)
                    kf[kk][j] = *(const short8*)(Kb + (size_t)(kv1 + j * 16 + lm) * DH_ + kk * 32 + lg * 8);
        }

        short8 pf[2][2];
        float alpha[2];
        #pragma unroll
        for (int t2 = 0; t2 < 2; ++t2) {
            float x[4][4];
            float rm = -1e30f;
            if (kt == ktmax) {
                const int q = qr0 + t2 * 16 + lm;
                #pragma unroll
                for (int j = 0; j < 4; ++j)
                    #pragma unroll
                    for (int r = 0; r < 4; ++r) {
                        float v = sc[t2][j][r] * 0.125f;
                        if (kv0 + j * 16 + lg * 4 + r > q) v = -1e30f;
                        x[j][r] = v; rm = fmaxf(rm, v);
                    }
            } else {
                #pragma unroll
                for (int j = 0; j < 4; ++j)
                    #pragma unroll
                    for (int r = 0; r < 4; ++r) {
                        float v = sc[t2][j][r] * 0.125f;
                        x[j][r] = v; rm = fmaxf(rm, v);
                    }
            }
            rm = fmaxf(rm, __shfl_xor(rm, 16, 64));
            rm = fmaxf(rm, __shfl_xor(rm, 32, 64));

            const float mn = fmaxf(m_i[t2], rm);
            alpha[t2] = __expf(m_i[t2] - mn);
            m_i[t2] = mn;
            float rs = 0.f;
            #pragma unroll
            for (int j = 0; j < 4; ++j)
                #pragma unroll
                for (int r = 0; r < 4; ++r) {
                    float e = __expf(x[j][r] - mn);
                    x[j][r] = e; rs += e;
                }
            rs += __shfl_xor(rs, 16, 64);
            rs += __shfl_xor(rs, 32, 64);
            l_i[t2] = l_i[t2] * alpha[t2] + rs;

            #pragma unroll
            for (int kk = 0; kk < 2; ++kk)
                #pragma unroll
                for (int jj = 0; jj < 4; ++jj) {
                    pf[t2][kk][jj]     = f2bf(x[2 * kk][jj]);
                    pf[t2][kk][4 + jj] = f2bf(x[2 * kk + 1][jj]);
                }
        }

        #pragma unroll
        for (int t2 = 0; t2 < 2; ++t2)
            #pragma unroll
            for (int i = 0; i < 4; ++i)
                o[t2][i] *= alpha[t2];

        #pragma unroll
        for (int kk = 0; kk < 2; ++kk)
            #pragma unroll
            for (int t2 = 0; t2 < 2; ++t2)
                #pragma unroll
                for (int i = 0; i < 4; ++i)
                    o[t2][i] = __builtin_amdgcn_mfma_f32_16x16x32_bf16(vf[kk][i], pf[t2][kk], o[t2][i], 0, 0, 0);
    }

    const int b = bh >> 4, h = bh & 15;
    #pragma unroll
    for (int t2 = 0; t2 < 2; ++t2) {
        const float inv = 1.f / l_i[t2];
        const size_t base = ((size_t)(b * S_ + qr0 + t2 * 16 + lm) << 10) + (h << 6) + lg * 4;
        #pragma unroll
        for (int i = 0; i < 4; ++i) {
            short4_t s4;
            #pragma unroll
            for (int r = 0; r < 4; ++r) s4[r] = f2bf(o[t2][i][r] * inv);
            *(short4_t*)(ctx + base + i * 16) = s4;
        }
    }
}

// ---------------------------------------------------------------------------
extern "C" void kernel_launch(void* const* d_in, const int* in_sizes, int n_in,
                              void* d_out, int out_size, void* d_ws, size_t ws_size,
                              hipStream_t stream) {
    const float* X  = (const float*)d_in[0];
    const float* Wq = (const float*)d_in[2];
    const float* bq = (const float*)d_in[3];
    const float* Wk = (const float*)d_in[4];
    const float* bk = (const float*)d_in[5];
    const float* Wv = (const float*)d_in[6];
    const float* bv = (const float*)d_in[7];
    const float* Wo = (const float*)d_in[8];
    const float* bo = (const float*)d_in[9];
    float* out = (float*)d_out;

    short* ws  = (short*)d_ws;
    short* Xb  = ws;                          // X bf16, 4,194,304
    short* Wb  = Xb + 4194304;                // [Wq|Wk|Wv|Wo] bf16
    short* Qh  = Wb + 4194304;                // [bh][s][64]
    short* Kb  = Qh + 4194304;                // [bh][s][64]
    short* Vt  = Kb + 4194304;                // [bh][64][s] (written by gemm)
    short* Ctx = Vt + 4194304;                // [b*s][1024]

    cast_kernel<<<4096, 256, 0, stream>>>(X, Wq, Wk, Wv, Wo, Xb, Wb);

    // fused QKV projection: flat grid 24*32 = 768, swizzled in-kernel
    gemm_kernel<0><<<768, 256, 0, stream>>>(
        Xb, Wb, bq, bk, bv, Qh, M_, 3 * D_, D_);

    attn_kernel<<<512, 256, 0, stream>>>(Qh, Kb, Vt, Ctx);

    // output projection: flat grid 8*32 = 256, swizzled in-kernel
    gemm_kernel<2><<<256, 256, 0, stream>>>(
        Ctx, Wb + 3145728, bo, bo, bo, out, M_, D_, D_);
}

// Round 10
// 268.398 us; speedup vs baseline: 1.5289x; 1.0042x over previous
//
#include <hip/hip_runtime.h>

// ---------------------------------------------------------------------------
// MultiHeadAttention: B=2, S=2048, H=16, Dh=64, D=1024, causal mask, fp32 I/O.
// R10: attention BK=128 (one softmax per 128 kv), exp2-domain softmax,
//      tree reductions, truncating P-pack.  Out-proj GEMM at BN=64 (2/CU).
//      GEMM staging stays m97-style global_load_lds (R9, verified).
// ---------------------------------------------------------------------------

#define B_   2
#define S_   2048
#define H_   16
#define DH_  64
#define D_   1024
#define M_   (B_ * S_)          // 4096 rows

typedef __attribute__((ext_vector_type(8))) short short8;
typedef __attribute__((ext_vector_type(4))) short short4_t;
typedef float v4f __attribute__((ext_vector_type(4)));

__device__ __forceinline__ short f2bf(float f) {
    union { float f; unsigned u; } v; v.f = f;
    unsigned r = v.u + 0x7fffu + ((v.u >> 16) & 1u);  // round-to-nearest-even
    return (short)(r >> 16);
}

#if __has_builtin(__builtin_amdgcn_exp2f)
#define EXP2(x) __builtin_amdgcn_exp2f(x)
#else
#define EXP2(x) exp2f(x)
#endif

// pack two f32 -> dword of two truncated bf16 (low short = a, high = b)
__device__ __forceinline__ unsigned pack2(float a, float b) {
    return (__float_as_uint(a) >> 16) | (__float_as_uint(b) & 0xFFFF0000u);
}

// async 16B/lane global -> LDS DMA (lane l deposits at lds + l*16)
__device__ __forceinline__ void gl2lds16(const short* g, short* l) {
    __builtin_amdgcn_global_load_lds(
        (const __attribute__((address_space(1))) unsigned int*)g,
        (__attribute__((address_space(3))) unsigned int*)l,
        16, 0, 0);
}

// ---------------------------------------------------------------------------
// Kernel 1: cast X and Wq,Wk,Wv,Wo fp32 -> bf16.  8 elems/thread, 16B stores.
// ---------------------------------------------------------------------------
__global__ __launch_bounds__(256) void cast_kernel(
    const float* __restrict__ X,
    const float* __restrict__ Wq, const float* __restrict__ Wk,
    const float* __restrict__ Wv, const float* __restrict__ Wo,
    short* __restrict__ Xb, short* __restrict__ Wb)
{
    const int NX8 = (M_ * D_) / 8;      // 524,288
    const int NW8 = (D_ * D_) / 8;      // 131,072
    int idx = blockIdx.x * 256 + threadIdx.x;   // 1,048,576 threads

    const float* src; short* dst; int off;
    if (idx < NX8) { src = X; dst = Xb; off = idx; }
    else {
        int r = idx - NX8;
        int sel = r >> 17;
        int o = r & (NW8 - 1);
        src = (sel == 0) ? Wq : (sel == 1) ? Wk : (sel == 2) ? Wv : Wo;
        dst = Wb + sel * (D_ * D_);
        off = o;
    }
    float4 f0 = ((const float4*)src)[off * 2];
    float4 f1 = ((const float4*)src)[off * 2 + 1];
    short8 s;
    s[0] = f2bf(f0.x); s[1] = f2bf(f0.y); s[2] = f2bf(f0.z); s[3] = f2bf(f0.w);
    s[4] = f2bf(f1.x); s[5] = f2bf(f1.y); s[6] = f2bf(f1.z); s[7] = f2bf(f1.w);
    *(short8*)(dst + (size_t)off * 8) = s;
}

// ---------------------------------------------------------------------------
// Kernel 2: C = A(bf16,[M,K]) @ W(bf16,[N,K])^T + bias.  BM=128, BK=64.
// m97 staging: global_load_lds dwordx4 into UNPADDED row-major LDS tiles.
// MODE 0 (BN=128): fused QKV, N=3072.  Q,K natural [bh][s][64]; V -> Vt
//                  [bh][64][s] via transposed LDS epilogue, 16B/lane stores.
// MODE 2 (BN=64):  fp32 out [M,1024] (final projection), 512 blocks (2/CU).
// XCD-aware flat-grid swizzle: xcd=bid&7 owns 4 m-rows.
// ---------------------------------------------------------------------------
template<int BN, int MODE>
__global__ __launch_bounds__(256) void gemm_kernel(
    const short* __restrict__ A, const short* __restrict__ W,
    const float* __restrict__ bq, const float* __restrict__ bk,
    const float* __restrict__ bv, void* __restrict__ out,
    int M, int N, int K)
{
    constexpr int SM = (MODE == 0) ? 18432 : (8192 + BN * 64);
    __shared__ __align__(16) short smem[SM];
    short* As = smem;                                  // [128][64]
    short* Bs = smem + 8192;                           // [BN][64]

    const int t    = threadIdx.x;
    const int lane = t & 63;
    const int wave = t >> 6;

    const int bid = blockIdx.x;
    const int by  = ((bid & 7) << 2) + ((bid >> 3) & 3);
    const int bx  = bid >> 5;
    const int m0 = by * 128;
    const int n0 = bx * BN;

    const int wm = (wave >> 1) * 64;
    const int wn = (wave & 1) * (BN / 2);
    constexpr int NJ  = BN / 32;       // acc cols per wave (4 or 2)
    constexpr int BIT = BN / 32;       // B staging insts per wave

    v4f acc[4][NJ] = {};

    // staging: inst i2 covers 8 rows; lane l -> row +(l>>3), col (l&7)*8
    const int rsub = lane >> 3;
    const int csub = (lane & 7) * 8;
    const short* Ag = A + (size_t)(m0 + wave * 32 + rsub) * K + csub;
    const short* Wg = W + (size_t)(n0 + wave * (BN / 4) + rsub) * K + csub;
    short* Asw = As + (wave * 32) * 64;
    short* Bsw = Bs + (wave * (BN / 4)) * 64;

    const int lm = lane & 15;
    const int lg = lane >> 4;

    for (int k0 = 0; k0 < K; k0 += 64) {
        #pragma unroll
        for (int i2 = 0; i2 < 4; ++i2)
            gl2lds16(Ag + (size_t)(i2 * 8) * K + k0, Asw + i2 * 512);
        #pragma unroll
        for (int i2 = 0; i2 < BIT; ++i2)
            gl2lds16(Wg + (size_t)(i2 * 8) * K + k0, Bsw + i2 * 512);
        __syncthreads();   // drains vmcnt(0): tiles visible

        #pragma unroll
        for (int kk = 0; kk < 2; ++kk) {
            const int fo = kk * 32 + lg * 8;
            short8 af[4], bf[NJ];
            #pragma unroll
            for (int i = 0; i < 4; ++i) af[i] = *(const short8*)&As[(wm + i * 16 + lm) * 64 + fo];
            #pragma unroll
            for (int j = 0; j < NJ; ++j) bf[j] = *(const short8*)&Bs[(wn + j * 16 + lm) * 64 + fo];
            #pragma unroll
            for (int i = 0; i < 4; ++i)
                #pragma unroll
                for (int j = 0; j < NJ; ++j)
                    acc[i][j] = __builtin_amdgcn_mfma_f32_16x16x32_bf16(af[i], bf[j], acc[i][j], 0, 0, 0);
        }
        __syncthreads();   // all reads done before next overwrite
    }

    const int sel = n0 >> 10;          // 0=Q 1=K 2=V (block-uniform, MODE 0)
    const float* bias = (MODE == 2) ? bq : (sel == 0) ? bq : (sel == 1) ? bk : bv;

    if constexpr (MODE == 2) {
        const int colb = n0 + wn + lm;
        const int rowb = m0 + wm + lg * 4;
        #pragma unroll
        for (int j = 0; j < NJ; ++j) {
            int col = colb + j * 16;
            float bv_ = bias[col];
            #pragma unroll
            for (int i = 0; i < 4; ++i)
                #pragma unroll
                for (int r = 0; r < 4; ++r)
                    ((float*)out)[(size_t)(rowb + i * 16 + r) * 1024 + col] = acc[i][j][r] + bv_;
        }
    } else {
        // bf16 via wave-private LDS region (72-padded); 16B/lane wide stores.
        short* Es = smem + wave * (64 * 72);
        const int cb = (n0 + wn) & 1023;
        #pragma unroll
        for (int j = 0; j < 4; ++j) {
            float bv_ = bias[cb + j * 16 + lm];
            #pragma unroll
            for (int i = 0; i < 4; ++i)
                #pragma unroll
                for (int r = 0; r < 4; ++r) {
                    float vv = acc[i][j][r] + bv_;
                    if (sel < 2)    // Es[s_local][d]
                        Es[(i * 16 + lg * 4 + r) * 72 + j * 16 + lm] = f2bf(vv);
                    else            // V: Es[d][s_local]  (transposed)
                        Es[(j * 16 + lm) * 72 + i * 16 + lg * 4 + r] = f2bf(vv);
                }
        }
        __asm__ __volatile__("s_waitcnt lgkmcnt(0)" ::: "memory");
        short* outQKV = (short*)out;           // [Qh | Kb | Vt]
        const int rl = lane >> 3;
        const int c8 = (lane & 7) * 8;
        const int h  = cb >> 6;
        const int b  = (m0 + wm) >> 11;
        const int bh = (b << 4) + h;
        if (sel < 2) {
            #pragma unroll
            for (int it = 0; it < 8; ++it) {
                int row_l = it * 8 + rl;
                short8 vrow = *(const short8*)&Es[row_l * 72 + c8];
                int s = (m0 + wm + row_l) & 2047;
                *(short8*)(outQKV + (size_t)sel * 4194304 +
                           ((size_t)bh * S_ + s) * DH_ + c8) = vrow;
            }
        } else {
            const int s0 = (m0 + wm) & 2047;
            #pragma unroll
            for (int it = 0; it < 8; ++it) {
                int d_l = it * 8 + rl;
                short8 vrow = *(const short8*)&Es[d_l * 72 + c8];
                *(short8*)(outQKV + (size_t)2 * 4194304 +
                           ((size_t)bh << 17) + ((size_t)d_l << 11) + s0 + c8) = vrow;
            }
        }
    }
}

// ---------------------------------------------------------------------------
// Kernel 3: causal flash attention, transposed-score form, 32 q-rows/wave,
// BK=128: one online-softmax step per 128 kv columns.  Zero LDS / barriers.
// Grid: 512 flat blocks (XCD-swizzled, 4 bh/XCD), paired long/short strips.
// exp2-domain softmax (scale folded), tree reductions, truncating P-pack.
// ---------------------------------------------------------------------------
__global__ __launch_bounds__(256, 2) void attn_kernel(
    const short* __restrict__ Q, const short* __restrict__ Kh,
    const short* __restrict__ Vt, short* __restrict__ ctx)
{
    const int t    = threadIdx.x;
    const int lane = t & 63;
    const int w    = t >> 6;
    const int bid  = blockIdx.x;                 // 512 blocks
    const int bh   = ((bid & 7) << 2) + ((bid >> 3) & 3);
    const int qp   = bid >> 5;                   // 0..15
    const int p    = (w < 2) ? (qp * 2 + w) : (63 - (qp * 2 + (w - 2)));
    const int qr0  = p * 32;
    const int ntiles = (p >> 1) + 1;             // 64-kv tiles; diag = last
    const int npairs = ntiles >> 1;
    const int rem    = ntiles & 1;

    const int lm = lane & 15;
    const int lg = lane >> 4;

    const float SCL = 0.1803368867f;   // 0.125 * log2(e)  (exp2 domain)

    const short* Qb = Q  + (size_t)bh * S_ * DH_;
    const short* Kb = Kh + (size_t)bh * S_ * DH_;
    const short* Vb = Vt + ((size_t)bh << 17);

    // Q as B-operand: B[n=q=qr0+t2*16+lm][k=kk*32+lg*8+j]
    short8 qf[2][2];
    #pragma unroll
    for (int t2 = 0; t2 < 2; ++t2)
        #pragma unroll
        for (int kk = 0; kk < 2; ++kk)
            qf[t2][kk] = *(const short8*)(Qb + (size_t)(qr0 + t2 * 16 + lm) * DH_ + kk * 32 + lg * 8);

    float m_i[2] = {-1e30f, -1e30f}, l_i[2] = {0.f, 0.f};
    v4f o[2][4] = {};   // O^T[d = i*16+lg*4+r][q = t2*16+lm]

    for (int it = 0; it < npairs; ++it) {
        const int kv0 = it * 128;
        const bool dpair = (rem == 0) && (it == npairs - 1);  // u=1 is diagonal

        // V^T A-frags, both subtiles (permuted k: slots 0-3 <- +4lg+jj, 4-7 <- +16)
        short8 vf[2][2][4];
        #pragma unroll
        for (int u = 0; u < 2; ++u)
            #pragma unroll
            for (int kk = 0; kk < 2; ++kk)
                #pragma unroll
                for (int i = 0; i < 4; ++i) {
                    const short* vp = Vb + ((size_t)(i * 16 + lm) << 11) + kv0 + u * 64 + kk * 32 + lg * 4;
                    short4_t a = *(const short4_t*)vp;
                    short4_t b = *(const short4_t*)(vp + 16);
                    vf[u][kk][i] = __builtin_shufflevector(a, b, 0, 1, 2, 3, 4, 5, 6, 7);
                }

        // S^T = K Q^T, both subtiles (32 MFMAs)
        v4f sc[2][2][4] = {};   // [t2][u][j]
        #pragma unroll
        for (int u = 0; u < 2; ++u) {
            short8 kf[2][4];
            #pragma unroll
            for (int kk = 0; kk < 2; ++kk)
                #pragma unroll
                for (int j = 0; j < 4; ++j)
                    kf[kk][j] = *(const short8*)(Kb + (size_t)(kv0 + u * 64 + j * 16 + lm) * DH_ + kk * 32 + lg * 8);
            #pragma unroll
            for (int kk = 0; kk < 2; ++kk)
                #pragma unroll
                for (int t2 = 0; t2 < 2; ++t2)
                    #pragma unroll
                    for (int j = 0; j < 4; ++j)
                        sc[t2][u][j] = __builtin_amdgcn_mfma_f32_16x16x32_bf16(kf[kk][j], qf[t2][kk], sc[t2][u][j], 0, 0, 0);
        }

        // one online-softmax step per t2 over 128 kv (in-lane 32 + 2 shuffles)
        float alpha[2];
        short8 pf[2][2][2];     // [t2][u][kk]
        #pragma unroll
        for (int t2 = 0; t2 < 2; ++t2) {
            float x[2][4][4];
            const int q = qr0 + t2 * 16 + lm;
            #pragma unroll
            for (int u = 0; u < 2; ++u)
                #pragma unroll
                for (int j = 0; j < 4; ++j)
                    #pragma unroll
                    for (int r = 0; r < 4; ++r) {
                        float v = sc[t2][u][j][r] * SCL;
                        if (dpair && u == 1 && (kv0 + 64 + j * 16 + lg * 4 + r > q)) v = -1e30f;
                        x[u][j][r] = v;
                    }
            // tree max over 32 in-lane values
            float m8[8];
            #pragma unroll
            for (int z = 0; z < 8; ++z) {
                const float* xz = x[z >> 2][z & 3];
                m8[z] = fmaxf(fmaxf(xz[0], xz[1]), fmaxf(xz[2], xz[3]));
            }
            float rm = fmaxf(fmaxf(fmaxf(m8[0], m8[1]), fmaxf(m8[2], m8[3])),
                             fmaxf(fmaxf(m8[4], m8[5]), fmaxf(m8[6], m8[7])));
            rm = fmaxf(rm, __shfl_xor(rm, 16, 64));
            rm = fmaxf(rm, __shfl_xor(rm, 32, 64));

            const float mn = fmaxf(m_i[t2], rm);
            alpha[t2] = EXP2(m_i[t2] - mn);
            m_i[t2] = mn;

            // exp2 + tree sum
            float s8[8];
            #pragma unroll
            for (int z = 0; z < 8; ++z) {
                float* xz = x[z >> 2][z & 3];
                xz[0] = EXP2(xz[0] - mn); xz[1] = EXP2(xz[1] - mn);
                xz[2] = EXP2(xz[2] - mn); xz[3] = EXP2(xz[3] - mn);
                s8[z] = (xz[0] + xz[1]) + (xz[2] + xz[3]);
            }
            float rs = ((s8[0] + s8[1]) + (s8[2] + s8[3])) + ((s8[4] + s8[5]) + (s8[6] + s8[7]));
            rs += __shfl_xor(rs, 16, 64);
            rs += __shfl_xor(rs, 32, 64);
            l_i[t2] = l_i[t2] * alpha[t2] + rs;

            // truncating pack: pf[t2][u][kk][jj] = x[u][2kk][jj], [4+jj]=x[u][2kk+1][jj]
            #pragma unroll
            for (int u = 0; u < 2; ++u)
                #pragma unroll
                for (int kk = 0; kk < 2; ++kk) {
                    union { short8 s; uint4 d; } pk;
                    pk.d.x = pack2(x[u][2 * kk][0],     x[u][2 * kk][1]);
                    pk.d.y = pack2(x[u][2 * kk][2],     x[u][2 * kk][3]);
                    pk.d.z = pack2(x[u][2 * kk + 1][0], x[u][2 * kk + 1][1]);
                    pk.d.w = pack2(x[u][2 * kk + 1][2], x[u][2 * kk + 1][3]);
                    pf[t2][u][kk] = pk.s;
                }
        }

        #pragma unroll
        for (int t2 = 0; t2 < 2; ++t2)
            #pragma unroll
            for (int i = 0; i < 4; ++i)
                o[t2][i] *= alpha[t2];

        // O^T += V^T P^T  (32 MFMAs)
        #pragma unroll
        for (int u = 0; u < 2; ++u)
            #pragma unroll
            for (int kk = 0; kk < 2; ++kk)
                #pragma unroll
                for (int t2 = 0; t2 < 2; ++t2)
                    #pragma unroll
                    for (int i = 0; i < 4; ++i)
                        o[t2][i] = __builtin_amdgcn_mfma_f32_16x16x32_bf16(vf[u][kk][i], pf[t2][u][kk], o[t2][i], 0, 0, 0);
    }

    if (rem) {   // trailing single 64-kv tile = the diagonal (masked)
        const int kv0 = npairs * 128;

        short8 vf1[2][4];
        #pragma unroll
        for (int kk = 0; kk < 2; ++kk)
            #pragma unroll
            for (int i = 0; i < 4; ++i) {
                const short* vp = Vb + ((size_t)(i * 16 + lm) << 11) + kv0 + kk * 32 + lg * 4;
                short4_t a = *(const short4_t*)vp;
                short4_t b = *(const short4_t*)(vp + 16);
                vf1[kk][i] = __builtin_shufflevector(a, b, 0, 1, 2, 3, 4, 5, 6, 7);
            }
        short8 kf[2][4];
        #pragma unroll
        for (int kk = 0; kk < 2; ++kk)
            #pragma unroll
            for (int j = 0; j < 4; ++j)
                kf[kk][j] = *(const short8*)(Kb + (size_t)(kv0 + j * 16 + lm) * DH_ + kk * 32 + lg * 8);

        v4f sc[2][4] = {};
        #pragma unroll
        for (int kk = 0; kk < 2; ++kk)
            #pragma unroll
            for (int t2 = 0; t2 < 2; ++t2)
                #pragma unroll
                for (int j = 0; j < 4; ++j)
                    sc[t2][j] = __builtin_amdgcn_mfma_f32_16x16x32_bf16(kf[kk][j], qf[t2][kk], sc[t2][j], 0, 0, 0);

        float alpha[2];
        short8 pf[2][2];
        #pragma unroll
        for (int t2 = 0; t2 < 2; ++t2) {
            float x[4][4];
            const int q = qr0 + t2 * 16 + lm;
            #pragma unroll
            for (int j = 0; j < 4; ++j)
                #pragma unroll
                for (int r = 0; r < 4; ++r) {
                    float v = sc[t2][j][r] * SCL;
                    if (kv0 + j * 16 + lg * 4 + r > q) v = -1e30f;
                    x[j][r] = v;
                }
            float m4[4];
            #pragma unroll
            for (int j = 0; j < 4; ++j)
                m4[j] = fmaxf(fmaxf(x[j][0], x[j][1]), fmaxf(x[j][2], x[j][3]));
            float rm = fmaxf(fmaxf(m4[0], m4[1]), fmaxf(m4[2], m4[3]));
            rm = fmaxf(rm, __shfl_xor(rm, 16, 64));
            rm = fmaxf(rm, __shfl_xor(rm, 32, 64));

            const float mn = fmaxf(m_i[t2], rm);
            alpha[t2] = EXP2(m_i[t2] - mn);
            m_i[t2] = mn;
            float s4[4];
            #pragma unroll
            for (int j = 0; j < 4; ++j) {
                x[j][0] = EXP2(x[j][0] - mn); x[j][1] = EXP2(x[j][1] - mn);
                x[j][2] = EXP2(x[j][2] - mn); x[j][3] = EXP2(x[j][3] - mn);
                s4[j] = (x[j][0] + x[j][1]) + (x[j][2] + x[j][3]);
            }
            float rs = (s4[0] + s4[1]) + (s4[2] + s4[3]);
            rs += __shfl_xor(rs, 16, 64);
            rs += __shfl_xor(rs, 32, 64);
            l_i[t2] = l_i[t2] * alpha[t2] + rs;

            #pragma unroll
            for (int kk = 0; kk < 2; ++kk) {
                union { short8 s; uint4 d; } pk;
                pk.d.x = pack2(x[2 * kk][0],     x[2 * kk][1]);
                pk.d.y = pack2(x[2 * kk][2],     x[2 * kk][3]);
                pk.d.z = pack2(x[2 * kk + 1][0], x[2 * kk + 1][1]);
                pk.d.w = pack2(x[2 * kk + 1][2], x[2 * kk + 1][3]);
                pf[t2][kk] = pk.s;
            }
        }

        #pragma unroll
        for (int t2 = 0; t2 < 2; ++t2)
            #pragma unroll
            for (int i = 0; i < 4; ++i)
                o[t2][i] *= alpha[t2];

        #pragma unroll
        for (int kk = 0; kk < 2; ++kk)
            #pragma unroll
            for (int t2 = 0; t2 < 2; ++t2)
                #pragma unroll
                for (int i = 0; i < 4; ++i)
                    o[t2][i] = __builtin_amdgcn_mfma_f32_16x16x32_bf16(vf1[kk][i], pf[t2][kk], o[t2][i], 0, 0, 0);
    }

    // epilogue: ctx[b*S + q][h*64 + d] = O/l, 8B stores
    const int b = bh >> 4, h = bh & 15;
    #pragma unroll
    for (int t2 = 0; t2 < 2; ++t2) {
        const float inv = 1.f / l_i[t2];
        const size_t base = ((size_t)(b * S_ + qr0 + t2 * 16 + lm) << 10) + (h << 6) + lg * 4;
        #pragma unroll
        for (int i = 0; i < 4; ++i) {
            short4_t s4;
            #pragma unroll
            for (int r = 0; r < 4; ++r) s4[r] = f2bf(o[t2][i][r] * inv);
            *(short4_t*)(ctx + base + i * 16) = s4;
        }
    }
}

// ---------------------------------------------------------------------------
extern "C" void kernel_launch(void* const* d_in, const int* in_sizes, int n_in,
                              void* d_out, int out_size, void* d_ws, size_t ws_size,
                              hipStream_t stream) {
    const float* X  = (const float*)d_in[0];
    const float* Wq = (const float*)d_in[2];
    const float* bq = (const float*)d_in[3];
    const float* Wk = (const float*)d_in[4];
    const float* bk = (const float*)d_in[5];
    const float* Wv = (const float*)d_in[6];
    const float* bv = (const float*)d_in[7];
    const float* Wo = (const float*)d_in[8];
    const float* bo = (const float*)d_in[9];
    float* out = (float*)d_out;

    short* ws  = (short*)d_ws;
    short* Xb  = ws;                          // X bf16, 4,194,304
    short* Wb  = Xb + 4194304;                // [Wq|Wk|Wv|Wo] bf16
    short* Qh  = Wb + 4194304;                // [bh][s][64]
    short* Kb  = Qh + 4194304;                // [bh][s][64]
    short* Vt  = Kb + 4194304;                // [bh][64][s] (written by gemm)
    short* Ctx = Vt + 4194304;                // [b*s][1024]

    cast_kernel<<<4096, 256, 0, stream>>>(X, Wq, Wk, Wv, Wo, Xb, Wb);

    // fused QKV projection: flat grid 24*32 = 768, swizzled in-kernel
    gemm_kernel<128, 0><<<768, 256, 0, stream>>>(
        Xb, Wb, bq, bk, bv, Qh, M_, 3 * D_, D_);

    attn_kernel<<<512, 256, 0, stream>>>(Qh, Kb, Vt, Ctx);

    // output projection: flat grid 16*32 = 512, swizzled in-kernel (2/CU)
    gemm_kernel<64, 2><<<512, 256, 0, stream>>>(
        Ctx, Wb + 3145728, bo, bo, bo, out, M_, D_, D_);
}